// Round 2
// baseline (1022.541 us; speedup 1.0000x reference)
//
#include <hip/hip_runtime.h>
#include <hip/hip_bf16.h>
#include <math.h>

// Problem constants
#define B_  4
#define S_  512
#define H_  768
#define NH_ 12
#define DH_ 64
#define FF_ 3072
#define L_  6
#define V_  30522
#define QKVN 2304          // fused QKV output width
#define M_  (B_ * S_)      // 2048 tokens

typedef short s16x8 __attribute__((ext_vector_type(8)));
typedef short s16x4v __attribute__((ext_vector_type(4)));
typedef float f32x4 __attribute__((ext_vector_type(4)));

__device__ __forceinline__ void gload_lds16(const void* g, void* l) {
    __builtin_amdgcn_global_load_lds(
        (const __attribute__((address_space(1))) void*)g,
        (__attribute__((address_space(3))) void*)l,
        16, 0, 0);
}

__device__ __forceinline__ ushort f2bu(float x) {
    __hip_bfloat16 h = __float2bfloat16(x);
    return *(ushort*)&h;
}

// read 8 contiguous bf16 from LDS as two 8B chunks (8B-aligned offsets only)
__device__ __forceinline__ s16x8 lds_frag(const ushort* p) {
    s16x4v lo = *(const s16x4v*)p;
    s16x4v hi = *(const s16x4v*)(p + 4);
    return __builtin_shufflevector(lo, hi, 0, 1, 2, 3, 4, 5, 6, 7);
}

// 16B-aligned LDS fragment read (GEMM k-slots are row*128B + slot*16B)
__device__ __forceinline__ s16x8 lds_frag16(const ushort* p) {
    return *(const s16x8*)p;
}

// ---------------------------------------------------------------------------
// Embedding gather + LayerNorm body (runs as the y==L_ plane of prep_embed).
// ---------------------------------------------------------------------------
__device__ __forceinline__ void embed_body(
    const int* __restrict__ ids, const int* __restrict__ tt,
    const float* __restrict__ wemb, const float* __restrict__ pemb,
    const float* __restrict__ temb, const float* __restrict__ g,
    const float* __restrict__ bb, float* __restrict__ x,
    __hip_bfloat16* __restrict__ xb, float* red)
{
    const int t = blockIdx.x;
    const int s = t % S_;
    const int tid = threadIdx.x;

    const float* wr = wemb + (size_t)ids[t] * H_;
    const float* pr = pemb + (size_t)s * H_;
    const float* tr = temb + (size_t)tt[t] * H_;

    float v[3];
    float sum = 0.f;
#pragma unroll
    for (int i = 0; i < 3; i++) {
        int c = tid + i * 256;
        v[i] = wr[c] + pr[c] + tr[c];
        sum += v[i];
    }
    red[tid] = sum; __syncthreads();
    for (int st = 128; st > 0; st >>= 1) { if (tid < st) red[tid] += red[tid + st]; __syncthreads(); }
    const float mean = red[0] / (float)H_;
    __syncthreads();
    float s2 = 0.f;
#pragma unroll
    for (int i = 0; i < 3; i++) { float d = v[i] - mean; s2 += d * d; }
    red[tid] = s2; __syncthreads();
    for (int st = 128; st > 0; st >>= 1) { if (tid < st) red[tid] += red[tid + st]; __syncthreads(); }
    const float rstd = rsqrtf(red[0] / (float)H_ + 1e-12f);
#pragma unroll
    for (int i = 0; i < 3; i++) {
        int c = tid + i * 256;
        float o = (v[i] - mean) * rstd * g[c] + bb[c];
        x[(size_t)t * H_ + c] = o;
        xb[(size_t)t * H_ + c] = __float2bfloat16(o);
    }
}

// ---------------------------------------------------------------------------
// Weight prep (all layers) + embedding, ONE launch.
// y < L_: transpose fp32 [K][N] -> bf16 [N][K] for layer y, 64x64 tiles,
//         float4 loads (256B segments) + ushort8 stores (128B segments).
// y == L_: embedding+LN plane (blockIdx.x = token).
// ---------------------------------------------------------------------------
__global__ __launch_bounds__(256) void prep_embed_kernel(
    const float* __restrict__ Wq, const float* __restrict__ Wk,
    const float* __restrict__ Wv, const float* __restrict__ Wo,
    const float* __restrict__ W1, const float* __restrict__ W2,
    const float* __restrict__ bq, const float* __restrict__ bk,
    const float* __restrict__ bv,
    ushort* __restrict__ Wt_qkv, ushort* __restrict__ Wt_o,
    ushort* __restrict__ Wt_1, ushort* __restrict__ Wt_2,
    float* __restrict__ b_qkv,
    const int* __restrict__ ids, const int* __restrict__ tt,
    const float* __restrict__ wemb, const float* __restrict__ pemb,
    const float* __restrict__ temb, const float* __restrict__ eg,
    const float* __restrict__ eb, float* __restrict__ x,
    __hip_bfloat16* __restrict__ xb)
{
    __shared__ float tile[64][68];     // 17.4 KB; also reused as reduce buf

    if (blockIdx.y == L_) {
        embed_body(ids, tt, wemb, pemb, temb, eg, eb, x, xb, (float*)tile);
        return;
    }

    const int l  = blockIdx.y;
    const int id = blockIdx.x;
    if (id >= 1737) return;
    const int tid = threadIdx.x;

    if (id >= 1728) {                  // bias concat: 9 blocks x 256
        int i = (id - 1728) * 256 + tid;
        if (i < QKVN)
            b_qkv[(size_t)l * QKVN + i] =
                (i < H_) ? bq[l * H_ + i]
                         : ((i < 2 * H_) ? bk[l * H_ + i - H_] : bv[l * H_ + i - 2 * H_]);
        return;
    }

    // pick source matrix / destination for this 64x64 tile
    const float* src; ushort* dst; int K, N, ncols, t;
    if (id < 432) {                    // QKV: 3 mats x 144 tiles of 768x768
        const int mat = id / 144; t = id % 144;
        src = (mat == 0) ? (Wq + (size_t)l * H_ * H_)
            : (mat == 1) ? (Wk + (size_t)l * H_ * H_)
                         : (Wv + (size_t)l * H_ * H_);
        dst = Wt_qkv + (size_t)l * 3 * H_ * H_ + (size_t)mat * H_ * H_;
        K = H_; N = H_; ncols = 12;
    } else if (id < 576) {             // O: 144 tiles
        t = id - 432;
        src = Wo + (size_t)l * H_ * H_;
        dst = Wt_o + (size_t)l * H_ * H_;
        K = H_; N = H_; ncols = 12;
    } else if (id < 1152) {            // W1: 768x3072, 576 tiles
        t = id - 576;
        src = W1 + (size_t)l * H_ * FF_;
        dst = Wt_1 + (size_t)l * H_ * FF_;
        K = H_; N = FF_; ncols = 48;
    } else {                           // W2: 3072x768, 576 tiles
        t = id - 1152;
        src = W2 + (size_t)l * FF_ * H_;
        dst = Wt_2 + (size_t)l * FF_ * H_;
        K = FF_; N = H_; ncols = 12;
    }

    const int n0 = (t % ncols) * 64;
    const int k0 = (t / ncols) * 64;

    // load: 64 rows x 64 floats, float4 per lane (16 lanes = 256B per row)
    const int lr = tid >> 4;           // 0..15
    const int lc = tid & 15;           // 0..15
#pragma unroll
    for (int i = 0; i < 4; i++)
        *(f32x4*)&tile[lr + 16 * i][lc * 4] =
            *(const f32x4*)&src[(size_t)(k0 + lr + 16 * i) * N + n0 + lc * 4];
    __syncthreads();

    // store: 64 n-rows x 64 bf16 (128B); lane covers 32B, 4 lanes per row.
    const int rn = tid >> 2;           // 0..63
    const int kc = tid & 3;            // 0..3 (16 k each)
    s16x8 o0, o1;
#pragma unroll
    for (int j = 0; j < 8; j++) o0[j] = (short)f2bu(tile[kc * 16 + j][rn]);
#pragma unroll
    for (int j = 0; j < 8; j++) o1[j] = (short)f2bu(tile[kc * 16 + 8 + j][rn]);
    ushort* dp = &dst[(size_t)(n0 + rn) * K + k0 + kc * 16];
    *(s16x8*)dp       = o0;
    *(s16x8*)(dp + 8) = o1;
}

// ---------------------------------------------------------------------------
// bf16 MFMA GEMM: C[M][N] = A[M][K] @ Bt[N][K]^T + bias.
// 128x128 tile, BK=64, double-buffered LDS (64KB), XOR-swizzled k-slots.
// 256 thr = 4 waves (2x2 of 64x64), 16x16x32 MFMA, 32 MFMA/wave/iter.
// NS = K-split count (blockIdx.z selects split; fp32 partials written to
// slab z of Cout; bias added by split 0 only).  EPI: 0=none 1=exact gelu
// (NS==1 only).  OUTBF: bf16 out (NS==1 only).
// ---------------------------------------------------------------------------
#define TM 128
#define TN 128
#define TK 64

template<int EPI, int OUTBF, int NS>
__global__ __launch_bounds__(256) void gemm_mfma_kernel(
    const ushort* __restrict__ A, const ushort* __restrict__ Bt,
    const float* __restrict__ bias, void* __restrict__ Cout,
    int M, int K, int N)
{
    __shared__ alignas(16) ushort As[2][TM * TK];
    __shared__ alignas(16) ushort Bs[2][TN * TK];
    const int tid  = threadIdx.x;
    const int lane = tid & 63;
    const int wave = tid >> 6;
    const int m0 = blockIdx.y * TM;
    const int n0 = blockIdx.x * TN;
    const int wm = (wave >> 1) * 64;
    const int wn = (wave & 1) * 64;

    const int Ksub = K / NS;
    if (NS > 1) {                         // K-split column offset
        A  += (size_t)blockIdx.z * Ksub;
        Bt += (size_t)blockIdx.z * Ksub;
    }

    f32x4 acc[4][4];
#pragma unroll
    for (int i = 0; i < 4; i++)
#pragma unroll
        for (int j = 0; j < 4; j++)
            acc[i][j] = (f32x4){0.f, 0.f, 0.f, 0.f};

    // ---- staging setup: wave stages rows [wave*32, wave*32+32) of A and B,
    // as 4 chunks of 8 rows (1KB each).  lane -> row r8=lane>>3, slot s=lane&7.
    // slot s of row r holds k-group g = s ^ (r&7); chunk bases are multiples
    // of 8 so r&7 == r8.
    const int r8 = lane >> 3;
    const int sl = lane & 7;
    const int gk = (sl ^ r8) * 8;          // element offset of this lane's k-group
    const ushort* aSrc[4];
    const ushort* bSrc[4];
    int dOff[4];
#pragma unroll
    for (int c = 0; c < 4; c++) {
        const int R = wave * 32 + c * 8;
        aSrc[c] = A  + (size_t)(m0 + R + r8) * K + gk;
        bSrc[c] = Bt + (size_t)(n0 + R + r8) * K + gk;
        dOff[c] = R * TK;                  // contiguous 1KB chunk base
    }

    const int fr = lane & 15;              // fragment row (m or n)
    const int q4 = lane >> 4;              // k-group within 32-k subtile
    // fragment LDS offsets (k-invariant): row*64 + ((ksub*4+q4)^(row&7))*8
    int offA[4][2], offB[4][2];
#pragma unroll
    for (int i = 0; i < 4; i++) {
        const int rowA = wm + i * 16 + fr;
        const int rowB = wn + i * 16 + fr;
#pragma unroll
        for (int ks = 0; ks < 2; ks++) {
            offA[i][ks] = rowA * TK + (((ks * 4 + q4) ^ (rowA & 7)) * 8);
            offB[i][ks] = rowB * TK + (((ks * 4 + q4) ^ (rowB & 7)) * 8);
        }
    }

    const int niter = Ksub / TK;

    // prologue: stage tile 0 into buffer 0
#pragma unroll
    for (int c = 0; c < 4; c++) {
        gload_lds16(aSrc[c], &As[0][dOff[c]]);
        gload_lds16(bSrc[c], &Bs[0][dOff[c]]);
    }

    int cur = 0;
    for (int it = 0; it < niter; ++it) {
        __syncthreads();      // drains the in-flight prefetch for buffer `cur`
        if (it + 1 < niter) { // prefetch next tile; stays in flight during compute
            const int koff = (it + 1) * TK;
#pragma unroll
            for (int c = 0; c < 4; c++) {
                gload_lds16(aSrc[c] + koff, &As[cur ^ 1][dOff[c]]);
                gload_lds16(bSrc[c] + koff, &Bs[cur ^ 1][dOff[c]]);
            }
        }

#pragma unroll
        for (int ks = 0; ks < 2; ks++) {
            s16x8 af[4], bf[4];
#pragma unroll
            for (int i = 0; i < 4; i++) af[i] = lds_frag16(&As[cur][offA[i][ks]]);
#pragma unroll
            for (int j = 0; j < 4; j++) bf[j] = lds_frag16(&Bs[cur][offB[j][ks]]);
#pragma unroll
            for (int i = 0; i < 4; i++)
#pragma unroll
                for (int j = 0; j < 4; j++)
                    acc[i][j] = __builtin_amdgcn_mfma_f32_16x16x32_bf16(
                        af[i], bf[j], acc[i][j], 0, 0, 0);
        }
        cur ^= 1;
    }

    // epilogue: C/D layout col=lane&15, row=(lane>>4)*4+reg
    const int ecol = lane & 15;
    const int erow = (lane >> 4) * 4;
    float* outF = (float*)Cout + (size_t)blockIdx.z * M * N;   // slab z (z=0 if NS==1)
#pragma unroll
    for (int j = 0; j < 4; j++) {
        const int gcol = n0 + wn + j * 16 + ecol;
        const float bv = (NS == 1 || blockIdx.z == 0) ? bias[gcol] : 0.f;
#pragma unroll
        for (int i = 0; i < 4; i++) {
#pragma unroll
            for (int r = 0; r < 4; r++) {
                const int grow = m0 + wm + i * 16 + erow + r;
                float v = acc[i][j][r] + bv;
                if (EPI == 1) v = v * 0.5f * (1.0f + erff(v * 0.70710678118654752f));
                if (OUTBF)
                    ((ushort*)Cout)[(size_t)grow * N + gcol] = f2bu(v);
                else
                    outF[(size_t)grow * N + gcol] = v;
            }
        }
    }
}

// ---------------------------------------------------------------------------
// MFMA flash attention (unchanged).
// ---------------------------------------------------------------------------
#define VST 68

__global__ __launch_bounds__(256) void flash_attn_mfma_kernel(
    const ushort* __restrict__ QKV, const int* __restrict__ amask,
    __hip_bfloat16* __restrict__ Octx)
{
    const int q0 = blockIdx.x * 64, h = blockIdx.y, b = blockIdx.z;
    const int tid = threadIdx.x, lane = tid & 63, wave = tid >> 6;
    __shared__ ushort Qs[64 * VST];       // [q][d]
    __shared__ ushort Ks[64 * VST];       // [key][d]
    __shared__ ushort Vt[64 * VST];       // [d][key]
    __shared__ ushort Ps[4][16 * VST];    // per-wave [q][key]
    __shared__ float biasS[S_];

    for (int i = tid; i < S_; i += 256)
        biasS[i] = amask[b * S_ + i] ? 0.f : -1e9f;

    {   // stage Q
        const ushort* qb = QKV + (size_t)(b * S_ + q0) * QKVN + h * DH_;
        const int q = tid >> 2, dg = (tid & 3) * 16;
        s16x8 v0 = *(const s16x8*)(qb + (size_t)q * QKVN + dg);
        s16x8 v1 = *(const s16x8*)(qb + (size_t)q * QKVN + dg + 8);
        ushort* d = &Qs[q * VST + dg];
        *(s16x4v*)(d)      = __builtin_shufflevector(v0, v0, 0, 1, 2, 3);
        *(s16x4v*)(d + 4)  = __builtin_shufflevector(v0, v0, 4, 5, 6, 7);
        *(s16x4v*)(d + 8)  = __builtin_shufflevector(v1, v1, 0, 1, 2, 3);
        *(s16x4v*)(d + 12) = __builtin_shufflevector(v1, v1, 4, 5, 6, 7);
    }
    __syncthreads();

    const int fm = lane & 15;
    const int fk = (lane >> 4) * 8;

    const s16x8 aq0 = lds_frag(&Qs[(wave * 16 + fm) * VST + fk]);
    const s16x8 aq1 = lds_frag(&Qs[(wave * 16 + fm) * VST + 32 + fk]);

    f32x4 acc[4];
#pragma unroll
    for (int j = 0; j < 4; j++) acc[j] = (f32x4){0.f, 0.f, 0.f, 0.f};
    float m_i[4], l_i[4];
#pragma unroll
    for (int r = 0; r < 4; r++) { m_i[r] = -INFINITY; l_i[r] = 0.f; }

    for (int kt = 0; kt < S_; kt += 64) {
        __syncthreads();
        {   // stage K tile [key][d]
            const ushort* kb = QKV + (size_t)(b * S_ + kt) * QKVN + H_ + h * DH_;
            const int ky = tid >> 2, dg = (tid & 3) * 16;
            s16x8 v0 = *(const s16x8*)(kb + (size_t)ky * QKVN + dg);
            s16x8 v1 = *(const s16x8*)(kb + (size_t)ky * QKVN + dg + 8);
            ushort* d = &Ks[ky * VST + dg];
            *(s16x4v*)(d)      = __builtin_shufflevector(v0, v0, 0, 1, 2, 3);
            *(s16x4v*)(d + 4)  = __builtin_shufflevector(v0, v0, 4, 5, 6, 7);
            *(s16x4v*)(d + 8)  = __builtin_shufflevector(v1, v1, 0, 1, 2, 3);
            *(s16x4v*)(d + 12) = __builtin_shufflevector(v1, v1, 4, 5, 6, 7);
        }
        {   // stage V transposed [d][key]
            const ushort* vb = QKV + (size_t)(b * S_ + kt) * QKVN + 2 * H_ + h * DH_;
            const int d = tid & 63, kg = tid >> 6;
#pragma unroll
            for (int kp = 0; kp < 8; kp++) {
                const int key = kg * 16 + kp * 2;
                ushort u0 = vb[(size_t)key * QKVN + d];
                ushort u1 = vb[(size_t)(key + 1) * QKVN + d];
                ushort2 u; u.x = u0; u.y = u1;
                *(ushort2*)&Vt[d * VST + key] = u;
            }
        }
        __syncthreads();

        f32x4 sc[4];
#pragma unroll
        for (int jj = 0; jj < 4; jj++) {
            s16x8 b0 = lds_frag(&Ks[(jj * 16 + fm) * VST + fk]);
            s16x8 b1 = lds_frag(&Ks[(jj * 16 + fm) * VST + 32 + fk]);
            f32x4 z = (f32x4){0.f, 0.f, 0.f, 0.f};
            z = __builtin_amdgcn_mfma_f32_16x16x32_bf16(aq0, b0, z, 0, 0, 0);
            z = __builtin_amdgcn_mfma_f32_16x16x32_bf16(aq1, b1, z, 0, 0, 0);
            sc[jj] = z;
        }

#pragma unroll
        for (int r = 0; r < 4; r++) {
            float mx = -INFINITY;
#pragma unroll
            for (int jj = 0; jj < 4; jj++) {
                float v = sc[jj][r] * 0.125f + biasS[kt + jj * 16 + fm];
                sc[jj][r] = v;
                mx = fmaxf(mx, v);
            }
#pragma unroll
            for (int msk = 1; msk < 16; msk <<= 1) mx = fmaxf(mx, __shfl_xor(mx, msk));
            const float newm = fmaxf(m_i[r], mx);
            const float alpha = __expf(m_i[r] - newm);
            m_i[r] = newm;
            float rs = 0.f;
#pragma unroll
            for (int jj = 0; jj < 4; jj++) {
                float p = __expf(sc[jj][r] - newm);
                sc[jj][r] = p; rs += p;
            }
#pragma unroll
            for (int msk = 1; msk < 16; msk <<= 1) rs += __shfl_xor(rs, msk);
            l_i[r] = l_i[r] * alpha + rs;
#pragma unroll
            for (int jj = 0; jj < 4; jj++) acc[jj][r] *= alpha;
        }

#pragma unroll
        for (int jj = 0; jj < 4; jj++)
#pragma unroll
            for (int r = 0; r < 4; r++)
                Ps[wave][((lane >> 4) * 4 + r) * VST + jj * 16 + fm] = f2bu(sc[jj][r]);

        const s16x8 ap0 = lds_frag(&Ps[wave][fm * VST + fk]);
        const s16x8 ap1 = lds_frag(&Ps[wave][fm * VST + 32 + fk]);

#pragma unroll
        for (int jj = 0; jj < 4; jj++) {
            s16x8 b0 = lds_frag(&Vt[(jj * 16 + fm) * VST + fk]);
            s16x8 b1 = lds_frag(&Vt[(jj * 16 + fm) * VST + 32 + fk]);
            acc[jj] = __builtin_amdgcn_mfma_f32_16x16x32_bf16(ap0, b0, acc[jj], 0, 0, 0);
            acc[jj] = __builtin_amdgcn_mfma_f32_16x16x32_bf16(ap1, b1, acc[jj], 0, 0, 0);
        }
    }

#pragma unroll
    for (int r = 0; r < 4; r++) {
        const int q = q0 + wave * 16 + (lane >> 4) * 4 + r;
        const float inv = 1.0f / l_i[r];
        __hip_bfloat16* op = Octx + (size_t)(b * S_ + q) * H_ + h * DH_;
#pragma unroll
        for (int jj = 0; jj < 4; jj++)
            op[jj * 16 + fm] = __float2bfloat16(acc[jj][r] * inv);
    }
}

// ---------------------------------------------------------------------------
// x = LN(x + sum of NS delta slabs) in place; writes bf16 shadow xb.
// QA=1: fuse the QA head (em[t] = LN_out . qa_w + qa_b) into the same pass.
// ---------------------------------------------------------------------------
template<int NS, int QA>
__global__ __launch_bounds__(256) void add_ln_kernel(
    float* __restrict__ x, const float* __restrict__ delta,
    const float* __restrict__ g, const float* __restrict__ bb,
    __hip_bfloat16* __restrict__ xb,
    const float* __restrict__ qa_w, const float* __restrict__ qa_b,
    float* __restrict__ em)
{
    const int t = blockIdx.x;
    const int tid = threadIdx.x;
    __shared__ float red[256];
    __shared__ float red2[256];
    const size_t base = (size_t)t * H_;

    float v[3];
    float sum = 0.f;
#pragma unroll
    for (int i = 0; i < 3; i++) {
        int c = tid + i * 256;
        float d = x[base + c];
#pragma unroll
        for (int s = 0; s < NS; s++)
            d += delta[(size_t)s * M_ * H_ + base + c];
        v[i] = d;
        sum += d;
    }
    red[tid] = sum; __syncthreads();
    for (int st = 128; st > 0; st >>= 1) { if (tid < st) red[tid] += red[tid + st]; __syncthreads(); }
    const float mean = red[0] / (float)H_;
    __syncthreads();
    float s2 = 0.f;
#pragma unroll
    for (int i = 0; i < 3; i++) { float d = v[i] - mean; s2 += d * d; }
    red[tid] = s2; __syncthreads();
    for (int st = 128; st > 0; st >>= 1) { if (tid < st) red[tid] += red[tid + st]; __syncthreads(); }
    const float rstd = rsqrtf(red[0] / (float)H_ + 1e-12f);
    float s0 = 0.f, s1 = 0.f;
#pragma unroll
    for (int i = 0; i < 3; i++) {
        int c = tid + i * 256;
        float o = (v[i] - mean) * rstd * g[c] + bb[c];
        x[base + c] = o;
        xb[base + c] = __float2bfloat16(o);
        if (QA) {
            s0 += o * qa_w[c * 2 + 0];
            s1 += o * qa_w[c * 2 + 1];
        }
    }
    if (QA) {
        __syncthreads();
        red[tid] = s0; red2[tid] = s1; __syncthreads();
        for (int st = 128; st > 0; st >>= 1) {
            if (tid < st) { red[tid] += red[tid + st]; red2[tid] += red2[tid + st]; }
            __syncthreads();
        }
        if (tid == 0) {
            em[(size_t)t * 2 + 0] = red[0] + qa_b[0];
            em[(size_t)t * 2 + 1] = red2[0] + qa_b[1];
        }
    }
}

// ---------------------------------------------------------------------------
// CRF via log-semiring parallel reduction (unchanged).
// ---------------------------------------------------------------------------
__device__ __forceinline__ float lse2(float a, float b) {
    float m = fmaxf(a, b);
    return m + log1pf(expf(-fabsf(a - b)));
}

__device__ __forceinline__ float4 lsem_comb(float4 a, float4 b) {
    float4 r;
    r.x = lse2(a.x + b.x, a.y + b.z);
    r.y = lse2(a.x + b.y, a.y + b.w);
    r.z = lse2(a.z + b.x, a.w + b.z);
    r.w = lse2(a.z + b.y, a.w + b.w);
    return r;
}

__global__ __launch_bounds__(256) void crf_parallel_kernel(
    const float* __restrict__ em, const int* __restrict__ amask,
    const int* __restrict__ spos, const int* __restrict__ epos,
    const float* __restrict__ startT, const float* __restrict__ endT,
    const float* __restrict__ trans, float* __restrict__ out)
{
    __shared__ float4 mats[B_][64];
    __shared__ float numred[B_][64];
    __shared__ float cntred[B_][64];
    __shared__ float llh[B_];
    const int tid = threadIdx.x;
    const int s = tid >> 6;
    const int j = tid & 63;
    const float NEG = -1e30f;

    const int sp = spos[s], ep = epos[s];
    const bool valid = (sp >= 0) && (sp < S_) && (ep >= 0) && (ep < S_) && (sp <= ep);
    const float* e = em + (size_t)s * S_ * 2;
    const int* mk = amask + s * S_;
    const float t00 = trans[0], t01 = trans[1], t10 = trans[2], t11 = trans[3];

    float4 C = make_float4(0.f, NEG, NEG, 0.f);
    float num = 0.f, cnt = 0.f;
#pragma unroll
    for (int k = 0; k < 8; k++) {
        const int t = j * 8 + 1 + k;
        float4 Mt = make_float4(0.f, NEG, NEG, 0.f);
        if (t < S_ && mk[t]) {
            const float e0 = e[2 * t], e1 = e[2 * t + 1];
            Mt = make_float4(t00 + e0, t01 + e1, t10 + e0, t11 + e1);
            const int tp = (valid && (t - 1) >= sp && (t - 1) <= ep) ? 1 : 0;
            const int tc = (valid && t >= sp && t <= ep) ? 1 : 0;
            const float tr = tp ? (tc ? t11 : t10) : (tc ? t01 : t00);
            num += tr + (tc ? e1 : e0);
            cnt += 1.f;
        }
        C = (k == 0) ? Mt : lsem_comb(C, Mt);
    }
    if (j == 0) {
        const int tag0 = (valid && 0 >= sp && 0 <= ep) ? 1 : 0;
        num += startT[tag0] + e[tag0];
        cnt += mk[0] ? 1.f : 0.f;
    }
    mats[s][j] = C;
    numred[s][j] = num;
    cntred[s][j] = cnt;
    __syncthreads();

    for (int st = 32; st >= 1; st >>= 1) {
        float4 a, b;
        const bool act = (j < st);
        if (act) { a = mats[s][2 * j]; b = mats[s][2 * j + 1]; }
        __syncthreads();
        if (act) mats[s][j] = lsem_comb(a, b);
        __syncthreads();
    }
    for (int st = 32; st >= 1; st >>= 1) {
        if (j < st) {
            numred[s][j] += numred[s][j + st];
            cntred[s][j] += cntred[s][j + st];
        }
        __syncthreads();
    }

    if (j == 0) {
        float numT = numred[s][0];
        const int last_idx = (int)(cntred[s][0] + 0.5f) - 1;
        const int ltag = (valid && last_idx >= sp && last_idx <= ep) ? 1 : 0;
        numT += endT[ltag];
        const float a00 = startT[0] + e[0];
        const float a01 = startT[1] + e[1];
        const float4 P = mats[s][0];
        const float aF0 = lse2(a00 + P.x, a01 + P.z);
        const float aF1 = lse2(a00 + P.y, a01 + P.w);
        const float logZ = lse2(aF0 + endT[0], aF1 + endT[1]);
        llh[s] = numT - logZ;
    }
    __syncthreads();
    if (tid == 0)
        out[0] = -(llh[0] + llh[1] + llh[2] + llh[3]);
}

// ---------------------------------------------------------------------------
// Launch
// ---------------------------------------------------------------------------
extern "C" void kernel_launch(void* const* d_in, const int* in_sizes, int n_in,
                              void* d_out, int out_size, void* d_ws, size_t ws_size,
                              hipStream_t stream)
{
    const int*   input_ids  = (const int*)  d_in[0];
    const int*   attn_mask  = (const int*)  d_in[1];
    const int*   token_type = (const int*)  d_in[2];
    const int*   start_pos  = (const int*)  d_in[3];
    const int*   end_pos    = (const int*)  d_in[4];
    const float* word_emb   = (const float*)d_in[5];
    const float* pos_emb    = (const float*)d_in[6];
    const float* type_emb   = (const float*)d_in[7];
    const float* emb_ln_g   = (const float*)d_in[8];
    const float* emb_ln_b   = (const float*)d_in[9];
    const float* Wq         = (const float*)d_in[10];
    const float* bq         = (const float*)d_in[11];
    const float* Wk         = (const float*)d_in[12];
    const float* bk         = (const float*)d_in[13];
    const float* Wv         = (const float*)d_in[14];
    const float* bv         = (const float*)d_in[15];
    const float* Wo         = (const float*)d_in[16];
    const float* bo         = (const float*)d_in[17];
    const float* ln1_g      = (const float*)d_in[18];
    const float* ln1_b      = (const float*)d_in[19];
    const float* W1         = (const float*)d_in[20];
    const float* b1         = (const float*)d_in[21];
    const float* W2         = (const float*)d_in[22];
    const float* b2         = (const float*)d_in[23];
    const float* ln2_g      = (const float*)d_in[24];
    const float* ln2_b      = (const float*)d_in[25];
    const float* qa_w       = (const float*)d_in[26];
    const float* qa_b       = (const float*)d_in[27];
    const float* crf_start  = (const float*)d_in[28];
    const float* crf_end    = (const float*)d_in[29];
    const float* crf_trans  = (const float*)d_in[30];
    float* out = (float*)d_out;

    // Workspace carve-up
    float*  x      = (float*)d_ws;                                  // M*H
    float*  tmp768 = x + (size_t)M_ * H_;                           // 4 * M*H (split-K slabs)
    float*  emis   = tmp768 + (size_t)4 * M_ * H_;                  // M*2
    float*  b_qkv  = emis + (size_t)M_ * 2;                         // L*2304
    ushort* xb     = (ushort*)(b_qkv + (size_t)L_ * QKVN);          // M*H
    ushort* qkvb   = xb + (size_t)M_ * H_;                          // M*2304
    ushort* ctxb   = qkvb + (size_t)M_ * QKVN;                      // M*H
    ushort* hb     = ctxb + (size_t)M_ * H_;                        // M*FF
    ushort* Wt_qkv = hb + (size_t)M_ * FF_;                         // L*2304*768
    ushort* Wt_o   = Wt_qkv + (size_t)L_ * QKVN * H_;               // L*768*768
    ushort* Wt_1   = Wt_o + (size_t)L_ * H_ * H_;                   // L*768*3072
    ushort* Wt_2   = Wt_1 + (size_t)L_ * H_ * FF_;                  // L*3072*768

    dim3 blk(256);

    // all-layer weight prep + embedding in one launch
    prep_embed_kernel<<<dim3(2048, L_ + 1), blk, 0, stream>>>(
        Wq, Wk, Wv, Wo, W1, W2, bq, bk, bv,
        Wt_qkv, Wt_o, Wt_1, Wt_2, b_qkv,
        input_ids, token_type, word_emb, pos_emb, type_emb,
        emb_ln_g, emb_ln_b, x, (__hip_bfloat16*)xb);

    const dim3 gQKV(QKVN / TN, M_ / TM);      // 18 x 16
    const dim3 gO(H_ / TN, M_ / TM, 2);       //  6 x 16 x 2 (split-K)
    const dim3 gF1(FF_ / TN, M_ / TM);        // 24 x 16
    const dim3 gF2(H_ / TN, M_ / TM, 4);      //  6 x 16 x 4 (split-K)
    const dim3 gA(S_ / 64, NH_, B_);          //  8 x 12 x 4

    for (int l = 0; l < L_; l++) {
        gemm_mfma_kernel<0, 1, 1><<<gQKV, blk, 0, stream>>>(
            xb, Wt_qkv + (size_t)l * QKVN * H_, b_qkv + (size_t)l * QKVN,
            qkvb, M_, H_, QKVN);

        flash_attn_mfma_kernel<<<gA, blk, 0, stream>>>(
            qkvb, attn_mask, (__hip_bfloat16*)ctxb);

        gemm_mfma_kernel<0, 0, 2><<<gO, blk, 0, stream>>>(
            ctxb, Wt_o + (size_t)l * H_ * H_, bo + l * H_, tmp768, M_, H_, H_);
        add_ln_kernel<2, 0><<<M_, blk, 0, stream>>>(
            x, tmp768, ln1_g + l * H_, ln1_b + l * H_,
            (__hip_bfloat16*)xb, nullptr, nullptr, nullptr);

        gemm_mfma_kernel<1, 1, 1><<<gF1, blk, 0, stream>>>(
            xb, Wt_1 + (size_t)l * H_ * FF_, b1 + l * FF_, hb, M_, H_, FF_);
        gemm_mfma_kernel<0, 0, 4><<<gF2, blk, 0, stream>>>(
            hb, Wt_2 + (size_t)l * FF_ * H_, b2 + l * H_, tmp768, M_, FF_, H_);
        if (l == L_ - 1)
            add_ln_kernel<4, 1><<<M_, blk, 0, stream>>>(
                x, tmp768, ln2_g + l * H_, ln2_b + l * H_,
                (__hip_bfloat16*)xb, qa_w, qa_b, emis);
        else
            add_ln_kernel<4, 0><<<M_, blk, 0, stream>>>(
                x, tmp768, ln2_g + l * H_, ln2_b + l * H_,
                (__hip_bfloat16*)xb, nullptr, nullptr, nullptr);
    }

    crf_parallel_kernel<<<1, 256, 0, stream>>>(emis, attn_mask, start_pos, end_pos,
                                               crf_start, crf_end, crf_trans, out);
}

// Round 3
// 1013.309 us; speedup vs baseline: 1.0091x; 1.0091x over previous
//
#include <hip/hip_runtime.h>
#include <hip/hip_bf16.h>
#include <math.h>

// Problem constants
#define B_  4
#define S_  512
#define H_  768
#define NH_ 12
#define DH_ 64
#define FF_ 3072
#define L_  6
#define V_  30522
#define QKVN 2304          // fused QKV output width
#define M_  (B_ * S_)      // 2048 tokens

typedef short s16x8 __attribute__((ext_vector_type(8)));
typedef short s16x4v __attribute__((ext_vector_type(4)));
typedef float f32x4 __attribute__((ext_vector_type(4)));

__device__ __forceinline__ void gload_lds16(const void* g, void* l) {
    __builtin_amdgcn_global_load_lds(
        (const __attribute__((address_space(1))) void*)g,
        (__attribute__((address_space(3))) void*)l,
        16, 0, 0);
}

__device__ __forceinline__ ushort f2bu(float x) {
    __hip_bfloat16 h = __float2bfloat16(x);
    return *(ushort*)&h;
}

// read 8 contiguous bf16 from LDS as two 8B chunks (8B-aligned offsets only)
__device__ __forceinline__ s16x8 lds_frag(const ushort* p) {
    s16x4v lo = *(const s16x4v*)p;
    s16x4v hi = *(const s16x4v*)(p + 4);
    return __builtin_shufflevector(lo, hi, 0, 1, 2, 3, 4, 5, 6, 7);
}

// 16B-aligned LDS fragment read (GEMM k-slots are row*128B + slot*16B)
__device__ __forceinline__ s16x8 lds_frag16(const ushort* p) {
    return *(const s16x8*)p;
}

// ---------------------------------------------------------------------------
// Embedding gather + LayerNorm body (runs as the y==L_ plane of prep_embed).
// ---------------------------------------------------------------------------
__device__ __forceinline__ void embed_body(
    const int* __restrict__ ids, const int* __restrict__ tt,
    const float* __restrict__ wemb, const float* __restrict__ pemb,
    const float* __restrict__ temb, const float* __restrict__ g,
    const float* __restrict__ bb, float* __restrict__ x,
    __hip_bfloat16* __restrict__ xb, float* red)
{
    const int t = blockIdx.x;
    const int s = t % S_;
    const int tid = threadIdx.x;

    const float* wr = wemb + (size_t)ids[t] * H_;
    const float* pr = pemb + (size_t)s * H_;
    const float* tr = temb + (size_t)tt[t] * H_;

    float v[3];
    float sum = 0.f;
#pragma unroll
    for (int i = 0; i < 3; i++) {
        int c = tid + i * 256;
        v[i] = wr[c] + pr[c] + tr[c];
        sum += v[i];
    }
    red[tid] = sum; __syncthreads();
    for (int st = 128; st > 0; st >>= 1) { if (tid < st) red[tid] += red[tid + st]; __syncthreads(); }
    const float mean = red[0] / (float)H_;
    __syncthreads();
    float s2 = 0.f;
#pragma unroll
    for (int i = 0; i < 3; i++) { float d = v[i] - mean; s2 += d * d; }
    red[tid] = s2; __syncthreads();
    for (int st = 128; st > 0; st >>= 1) { if (tid < st) red[tid] += red[tid + st]; __syncthreads(); }
    const float rstd = rsqrtf(red[0] / (float)H_ + 1e-12f);
#pragma unroll
    for (int i = 0; i < 3; i++) {
        int c = tid + i * 256;
        float o = (v[i] - mean) * rstd * g[c] + bb[c];
        x[(size_t)t * H_ + c] = o;
        xb[(size_t)t * H_ + c] = __float2bfloat16(o);
    }
}

// ---------------------------------------------------------------------------
// Weight prep (all layers) + embedding, ONE launch.
// y < L_: transpose fp32 [K][N] -> bf16 TILED [N/64][K/64][64][64] for layer
//         y.  Each block: float4 reads of a 64x64 fp32 tile + ONE contiguous
//         8KB tile write (256 thr x 32B sequential).
// y == L_: embedding+LN plane (blockIdx.x = token).
// ---------------------------------------------------------------------------
__global__ __launch_bounds__(256) void prep_embed_kernel(
    const float* __restrict__ Wq, const float* __restrict__ Wk,
    const float* __restrict__ Wv, const float* __restrict__ Wo,
    const float* __restrict__ W1, const float* __restrict__ W2,
    const float* __restrict__ bq, const float* __restrict__ bk,
    const float* __restrict__ bv,
    ushort* __restrict__ Wt_qkv, ushort* __restrict__ Wt_o,
    ushort* __restrict__ Wt_1, ushort* __restrict__ Wt_2,
    float* __restrict__ b_qkv,
    const int* __restrict__ ids, const int* __restrict__ tt,
    const float* __restrict__ wemb, const float* __restrict__ pemb,
    const float* __restrict__ temb, const float* __restrict__ eg,
    const float* __restrict__ eb, float* __restrict__ x,
    __hip_bfloat16* __restrict__ xb)
{
    __shared__ float tile[64][68];     // 17.4 KB; also reused as reduce buf

    if (blockIdx.y == L_) {
        embed_body(ids, tt, wemb, pemb, temb, eg, eb, x, xb, (float*)tile);
        return;
    }

    const int l  = blockIdx.y;
    const int id = blockIdx.x;
    if (id >= 1737) return;
    const int tid = threadIdx.x;

    if (id >= 1728) {                  // bias concat: 9 blocks x 256
        int i = (id - 1728) * 256 + tid;
        if (i < QKVN)
            b_qkv[(size_t)l * QKVN + i] =
                (i < H_) ? bq[l * H_ + i]
                         : ((i < 2 * H_) ? bk[l * H_ + i - H_] : bv[l * H_ + i - 2 * H_]);
        return;
    }

    // pick source matrix / destination for this 64x64 tile
    const float* src; ushort* dst; int N, ncols, ktiles, t;
    if (id < 432) {                    // QKV: 3 mats x 144 tiles of 768x768
        const int mat = id / 144; t = id % 144;
        src = (mat == 0) ? (Wq + (size_t)l * H_ * H_)
            : (mat == 1) ? (Wk + (size_t)l * H_ * H_)
                         : (Wv + (size_t)l * H_ * H_);
        dst = Wt_qkv + (size_t)l * 3 * H_ * H_ + (size_t)mat * H_ * H_;
        N = H_; ncols = 12; ktiles = 12;
    } else if (id < 576) {             // O: 144 tiles
        t = id - 432;
        src = Wo + (size_t)l * H_ * H_;
        dst = Wt_o + (size_t)l * H_ * H_;
        N = H_; ncols = 12; ktiles = 12;
    } else if (id < 1152) {            // W1: 768x3072, 576 tiles
        t = id - 576;
        src = W1 + (size_t)l * H_ * FF_;
        dst = Wt_1 + (size_t)l * H_ * FF_;
        N = FF_; ncols = 48; ktiles = 12;
    } else {                           // W2: 3072x768, 576 tiles
        t = id - 1152;
        src = W2 + (size_t)l * FF_ * H_;
        dst = Wt_2 + (size_t)l * FF_ * H_;
        N = H_; ncols = 12; ktiles = 48;
    }

    const int n0 = (t % ncols) * 64;
    const int k0 = (t / ncols) * 64;

    // load: 64 rows x 64 floats, float4 per lane (16 lanes = 256B per row)
    const int lr = tid >> 4;           // 0..15
    const int lc = tid & 15;           // 0..15
#pragma unroll
    for (int i = 0; i < 4; i++)
        *(f32x4*)&tile[lr + 16 * i][lc * 4] =
            *(const f32x4*)&src[(size_t)(k0 + lr + 16 * i) * N + n0 + lc * 4];
    __syncthreads();

    // store: ONE contiguous 8KB tile, thread tid writes bytes [32*tid,32*tid+32)
    // within-tile layout [n%64][k%64]: row rn = tid>>2, k-cols kc*16..+16.
    const int rn = tid >> 2;           // 0..63
    const int kc = tid & 3;            // 0..3 (16 k each)
    s16x8 o0, o1;
#pragma unroll
    for (int j = 0; j < 8; j++) o0[j] = (short)f2bu(tile[kc * 16 + j][rn]);
#pragma unroll
    for (int j = 0; j < 8; j++) o1[j] = (short)f2bu(tile[kc * 16 + 8 + j][rn]);
    ushort* dp = dst + ((size_t)(n0 >> 6) * ktiles + (k0 >> 6)) * 4096 + tid * 16;
    *(s16x8*)dp       = o0;
    *(s16x8*)(dp + 8) = o1;
}

// ---------------------------------------------------------------------------
// bf16 MFMA GEMM: C[M][N] = A[M][K] @ B^T + bias, where B is stored TILED:
// Bt[n/64][k/64][64][64] (each 64x64 bf16 tile contiguous, 8KB).
// 128x128 tile, BK=64, double-buffered LDS (64KB), XOR-swizzled k-slots.
// 256 thr = 4 waves (2x2 of 64x64), 16x16x32 MFMA, 32 MFMA/wave/iter.
// NS = K-split count (blockIdx.z selects split; fp32 partials written to
// slab z of Cout; bias added by split 0 only).  EPI: 0=none 1=exact gelu
// (NS==1 only).  OUTBF: bf16 out (NS==1 only).
// ---------------------------------------------------------------------------
#define TM 128
#define TN 128
#define TK 64

template<int EPI, int OUTBF, int NS>
__global__ __launch_bounds__(256) void gemm_mfma_kernel(
    const ushort* __restrict__ A, const ushort* __restrict__ Bt,
    const float* __restrict__ bias, void* __restrict__ Cout,
    int M, int K, int N)
{
    __shared__ alignas(16) ushort As[2][TM * TK];
    __shared__ alignas(16) ushort Bs[2][TN * TK];
    const int tid  = threadIdx.x;
    const int lane = tid & 63;
    const int wave = tid >> 6;
    const int m0 = blockIdx.y * TM;
    const int n0 = blockIdx.x * TN;
    const int wm = (wave >> 1) * 64;
    const int wn = (wave & 1) * 64;

    const int Ksub = K / NS;
    const int Kt   = K >> 6;              // k-tiles in tiled B layout
    int kt0 = 0;
    if (NS > 1) {                         // K-split offsets
        A  += (size_t)blockIdx.z * Ksub;  // A row-major
        kt0 = blockIdx.z * (Ksub >> 6);   // B tiled
    }

    f32x4 acc[4][4];
#pragma unroll
    for (int i = 0; i < 4; i++)
#pragma unroll
        for (int j = 0; j < 4; j++)
            acc[i][j] = (f32x4){0.f, 0.f, 0.f, 0.f};

    // ---- staging setup: wave stages rows [wave*32, wave*32+32) of A and B,
    // as 4 chunks of 8 rows (1KB each).  lane -> row r8=lane>>3, slot s=lane&7.
    // slot s of row r holds k-group g = s ^ (r&7); chunk bases are multiples
    // of 8 so r&7 == r8.
    const int r8 = lane >> 3;
    const int sl = lane & 7;
    const int gk = (sl ^ r8) * 8;          // element offset of this lane's k-group
    const ushort* aSrc[4];
    const ushort* bSrc[4];                 // tiled: advance 4096 elems per K-step
    int dOff[4];
#pragma unroll
    for (int c = 0; c < 4; c++) {
        const int R = wave * 32 + c * 8;
        aSrc[c] = A + (size_t)(m0 + R + r8) * K + gk;
        const int n = n0 + R + r8;
        bSrc[c] = Bt + ((size_t)(n >> 6) * Kt + kt0) * 4096 + (n & 63) * 64 + gk;
        dOff[c] = R * TK;                  // contiguous 1KB chunk base
    }

    const int fr = lane & 15;              // fragment row (m or n)
    const int q4 = lane >> 4;              // k-group within 32-k subtile
    // fragment LDS offsets (k-invariant): row*64 + ((ksub*4+q4)^(row&7))*8
    int offA[4][2], offB[4][2];
#pragma unroll
    for (int i = 0; i < 4; i++) {
        const int rowA = wm + i * 16 + fr;
        const int rowB = wn + i * 16 + fr;
#pragma unroll
        for (int ks = 0; ks < 2; ks++) {
            offA[i][ks] = rowA * TK + (((ks * 4 + q4) ^ (rowA & 7)) * 8);
            offB[i][ks] = rowB * TK + (((ks * 4 + q4) ^ (rowB & 7)) * 8);
        }
    }

    const int niter = Ksub / TK;

    // prologue: stage tile 0 into buffer 0
#pragma unroll
    for (int c = 0; c < 4; c++) {
        gload_lds16(aSrc[c], &As[0][dOff[c]]);
        gload_lds16(bSrc[c], &Bs[0][dOff[c]]);
    }

    int cur = 0;
    for (int it = 0; it < niter; ++it) {
        __syncthreads();      // drains the in-flight prefetch for buffer `cur`
        if (it + 1 < niter) { // prefetch next tile; stays in flight during compute
            const int koff = (it + 1) * TK;
            const size_t boff = (size_t)(it + 1) * 4096;
#pragma unroll
            for (int c = 0; c < 4; c++) {
                gload_lds16(aSrc[c] + koff, &As[cur ^ 1][dOff[c]]);
                gload_lds16(bSrc[c] + boff, &Bs[cur ^ 1][dOff[c]]);
            }
        }

#pragma unroll
        for (int ks = 0; ks < 2; ks++) {
            s16x8 af[4], bf[4];
#pragma unroll
            for (int i = 0; i < 4; i++) af[i] = lds_frag16(&As[cur][offA[i][ks]]);
#pragma unroll
            for (int j = 0; j < 4; j++) bf[j] = lds_frag16(&Bs[cur][offB[j][ks]]);
#pragma unroll
            for (int i = 0; i < 4; i++)
#pragma unroll
                for (int j = 0; j < 4; j++)
                    acc[i][j] = __builtin_amdgcn_mfma_f32_16x16x32_bf16(
                        af[i], bf[j], acc[i][j], 0, 0, 0);
        }
        cur ^= 1;
    }

    // epilogue: C/D layout col=lane&15, row=(lane>>4)*4+reg
    const int ecol = lane & 15;
    const int erow = (lane >> 4) * 4;
    float* outF = (float*)Cout + (size_t)blockIdx.z * M * N;   // slab z (z=0 if NS==1)
#pragma unroll
    for (int j = 0; j < 4; j++) {
        const int gcol = n0 + wn + j * 16 + ecol;
        const float bv = (NS == 1 || blockIdx.z == 0) ? bias[gcol] : 0.f;
#pragma unroll
        for (int i = 0; i < 4; i++) {
#pragma unroll
            for (int r = 0; r < 4; r++) {
                const int grow = m0 + wm + i * 16 + erow + r;
                float v = acc[i][j][r] + bv;
                if (EPI == 1) v = v * 0.5f * (1.0f + erff(v * 0.70710678118654752f));
                if (OUTBF)
                    ((ushort*)Cout)[(size_t)grow * N + gcol] = f2bu(v);
                else
                    outF[(size_t)grow * N + gcol] = v;
            }
        }
    }
}

// ---------------------------------------------------------------------------
// MFMA flash attention (unchanged).
// ---------------------------------------------------------------------------
#define VST 68

__global__ __launch_bounds__(256) void flash_attn_mfma_kernel(
    const ushort* __restrict__ QKV, const int* __restrict__ amask,
    __hip_bfloat16* __restrict__ Octx)
{
    const int q0 = blockIdx.x * 64, h = blockIdx.y, b = blockIdx.z;
    const int tid = threadIdx.x, lane = tid & 63, wave = tid >> 6;
    __shared__ ushort Qs[64 * VST];       // [q][d]
    __shared__ ushort Ks[64 * VST];       // [key][d]
    __shared__ ushort Vt[64 * VST];       // [d][key]
    __shared__ ushort Ps[4][16 * VST];    // per-wave [q][key]
    __shared__ float biasS[S_];

    for (int i = tid; i < S_; i += 256)
        biasS[i] = amask[b * S_ + i] ? 0.f : -1e9f;

    {   // stage Q
        const ushort* qb = QKV + (size_t)(b * S_ + q0) * QKVN + h * DH_;
        const int q = tid >> 2, dg = (tid & 3) * 16;
        s16x8 v0 = *(const s16x8*)(qb + (size_t)q * QKVN + dg);
        s16x8 v1 = *(const s16x8*)(qb + (size_t)q * QKVN + dg + 8);
        ushort* d = &Qs[q * VST + dg];
        *(s16x4v*)(d)      = __builtin_shufflevector(v0, v0, 0, 1, 2, 3);
        *(s16x4v*)(d + 4)  = __builtin_shufflevector(v0, v0, 4, 5, 6, 7);
        *(s16x4v*)(d + 8)  = __builtin_shufflevector(v1, v1, 0, 1, 2, 3);
        *(s16x4v*)(d + 12) = __builtin_shufflevector(v1, v1, 4, 5, 6, 7);
    }
    __syncthreads();

    const int fm = lane & 15;
    const int fk = (lane >> 4) * 8;

    const s16x8 aq0 = lds_frag(&Qs[(wave * 16 + fm) * VST + fk]);
    const s16x8 aq1 = lds_frag(&Qs[(wave * 16 + fm) * VST + 32 + fk]);

    f32x4 acc[4];
#pragma unroll
    for (int j = 0; j < 4; j++) acc[j] = (f32x4){0.f, 0.f, 0.f, 0.f};
    float m_i[4], l_i[4];
#pragma unroll
    for (int r = 0; r < 4; r++) { m_i[r] = -INFINITY; l_i[r] = 0.f; }

    for (int kt = 0; kt < S_; kt += 64) {
        __syncthreads();
        {   // stage K tile [key][d]
            const ushort* kb = QKV + (size_t)(b * S_ + kt) * QKVN + H_ + h * DH_;
            const int ky = tid >> 2, dg = (tid & 3) * 16;
            s16x8 v0 = *(const s16x8*)(kb + (size_t)ky * QKVN + dg);
            s16x8 v1 = *(const s16x8*)(kb + (size_t)ky * QKVN + dg + 8);
            ushort* d = &Ks[ky * VST + dg];
            *(s16x4v*)(d)      = __builtin_shufflevector(v0, v0, 0, 1, 2, 3);
            *(s16x4v*)(d + 4)  = __builtin_shufflevector(v0, v0, 4, 5, 6, 7);
            *(s16x4v*)(d + 8)  = __builtin_shufflevector(v1, v1, 0, 1, 2, 3);
            *(s16x4v*)(d + 12) = __builtin_shufflevector(v1, v1, 4, 5, 6, 7);
        }
        {   // stage V transposed [d][key]
            const ushort* vb = QKV + (size_t)(b * S_ + kt) * QKVN + 2 * H_ + h * DH_;
            const int d = tid & 63, kg = tid >> 6;
#pragma unroll
            for (int kp = 0; kp < 8; kp++) {
                const int key = kg * 16 + kp * 2;
                ushort u0 = vb[(size_t)key * QKVN + d];
                ushort u1 = vb[(size_t)(key + 1) * QKVN + d];
                ushort2 u; u.x = u0; u.y = u1;
                *(ushort2*)&Vt[d * VST + key] = u;
            }
        }
        __syncthreads();

        f32x4 sc[4];
#pragma unroll
        for (int jj = 0; jj < 4; jj++) {
            s16x8 b0 = lds_frag(&Ks[(jj * 16 + fm) * VST + fk]);
            s16x8 b1 = lds_frag(&Ks[(jj * 16 + fm) * VST + 32 + fk]);
            f32x4 z = (f32x4){0.f, 0.f, 0.f, 0.f};
            z = __builtin_amdgcn_mfma_f32_16x16x32_bf16(aq0, b0, z, 0, 0, 0);
            z = __builtin_amdgcn_mfma_f32_16x16x32_bf16(aq1, b1, z, 0, 0, 0);
            sc[jj] = z;
        }

#pragma unroll
        for (int r = 0; r < 4; r++) {
            float mx = -INFINITY;
#pragma unroll
            for (int jj = 0; jj < 4; jj++) {
                float v = sc[jj][r] * 0.125f + biasS[kt + jj * 16 + fm];
                sc[jj][r] = v;
                mx = fmaxf(mx, v);
            }
#pragma unroll
            for (int msk = 1; msk < 16; msk <<= 1) mx = fmaxf(mx, __shfl_xor(mx, msk));
            const float newm = fmaxf(m_i[r], mx);
            const float alpha = __expf(m_i[r] - newm);
            m_i[r] = newm;
            float rs = 0.f;
#pragma unroll
            for (int jj = 0; jj < 4; jj++) {
                float p = __expf(sc[jj][r] - newm);
                sc[jj][r] = p; rs += p;
            }
#pragma unroll
            for (int msk = 1; msk < 16; msk <<= 1) rs += __shfl_xor(rs, msk);
            l_i[r] = l_i[r] * alpha + rs;
#pragma unroll
            for (int jj = 0; jj < 4; jj++) acc[jj][r] *= alpha;
        }

#pragma unroll
        for (int jj = 0; jj < 4; jj++)
#pragma unroll
            for (int r = 0; r < 4; r++)
                Ps[wave][((lane >> 4) * 4 + r) * VST + jj * 16 + fm] = f2bu(sc[jj][r]);

        const s16x8 ap0 = lds_frag(&Ps[wave][fm * VST + fk]);
        const s16x8 ap1 = lds_frag(&Ps[wave][fm * VST + 32 + fk]);

#pragma unroll
        for (int jj = 0; jj < 4; jj++) {
            s16x8 b0 = lds_frag(&Vt[(jj * 16 + fm) * VST + fk]);
            s16x8 b1 = lds_frag(&Vt[(jj * 16 + fm) * VST + 32 + fk]);
            acc[jj] = __builtin_amdgcn_mfma_f32_16x16x32_bf16(ap0, b0, acc[jj], 0, 0, 0);
            acc[jj] = __builtin_amdgcn_mfma_f32_16x16x32_bf16(ap1, b1, acc[jj], 0, 0, 0);
        }
    }

#pragma unroll
    for (int r = 0; r < 4; r++) {
        const int q = q0 + wave * 16 + (lane >> 4) * 4 + r;
        const float inv = 1.0f / l_i[r];
        __hip_bfloat16* op = Octx + (size_t)(b * S_ + q) * H_ + h * DH_;
#pragma unroll
        for (int jj = 0; jj < 4; jj++)
            op[jj * 16 + fm] = __float2bfloat16(acc[jj][r] * inv);
    }
}

// ---------------------------------------------------------------------------
// x = LN(x + sum of NS delta slabs) in place; writes bf16 shadow xb.
// QA=1: fuse the QA head (em[t] = LN_out . qa_w + qa_b) into the same pass.
// ---------------------------------------------------------------------------
template<int NS, int QA>
__global__ __launch_bounds__(256) void add_ln_kernel(
    float* __restrict__ x, const float* __restrict__ delta,
    const float* __restrict__ g, const float* __restrict__ bb,
    __hip_bfloat16* __restrict__ xb,
    const float* __restrict__ qa_w, const float* __restrict__ qa_b,
    float* __restrict__ em)
{
    const int t = blockIdx.x;
    const int tid = threadIdx.x;
    __shared__ float red[256];
    __shared__ float red2[256];
    const size_t base = (size_t)t * H_;

    float v[3];
    float sum = 0.f;
#pragma unroll
    for (int i = 0; i < 3; i++) {
        int c = tid + i * 256;
        float d = x[base + c];
#pragma unroll
        for (int s = 0; s < NS; s++)
            d += delta[(size_t)s * M_ * H_ + base + c];
        v[i] = d;
        sum += d;
    }
    red[tid] = sum; __syncthreads();
    for (int st = 128; st > 0; st >>= 1) { if (tid < st) red[tid] += red[tid + st]; __syncthreads(); }
    const float mean = red[0] / (float)H_;
    __syncthreads();
    float s2 = 0.f;
#pragma unroll
    for (int i = 0; i < 3; i++) { float d = v[i] - mean; s2 += d * d; }
    red[tid] = s2; __syncthreads();
    for (int st = 128; st > 0; st >>= 1) { if (tid < st) red[tid] += red[tid + st]; __syncthreads(); }
    const float rstd = rsqrtf(red[0] / (float)H_ + 1e-12f);
    float s0 = 0.f, s1 = 0.f;
#pragma unroll
    for (int i = 0; i < 3; i++) {
        int c = tid + i * 256;
        float o = (v[i] - mean) * rstd * g[c] + bb[c];
        x[base + c] = o;
        xb[base + c] = __float2bfloat16(o);
        if (QA) {
            s0 += o * qa_w[c * 2 + 0];
            s1 += o * qa_w[c * 2 + 1];
        }
    }
    if (QA) {
        __syncthreads();
        red[tid] = s0; red2[tid] = s1; __syncthreads();
        for (int st = 128; st > 0; st >>= 1) {
            if (tid < st) { red[tid] += red[tid + st]; red2[tid] += red2[tid + st]; }
            __syncthreads();
        }
        if (tid == 0) {
            em[(size_t)t * 2 + 0] = red[0] + qa_b[0];
            em[(size_t)t * 2 + 1] = red2[0] + qa_b[1];
        }
    }
}

// ---------------------------------------------------------------------------
// CRF via log-semiring parallel reduction (unchanged).
// ---------------------------------------------------------------------------
__device__ __forceinline__ float lse2(float a, float b) {
    float m = fmaxf(a, b);
    return m + log1pf(expf(-fabsf(a - b)));
}

__device__ __forceinline__ float4 lsem_comb(float4 a, float4 b) {
    float4 r;
    r.x = lse2(a.x + b.x, a.y + b.z);
    r.y = lse2(a.x + b.y, a.y + b.w);
    r.z = lse2(a.z + b.x, a.w + b.z);
    r.w = lse2(a.z + b.y, a.w + b.w);
    return r;
}

__global__ __launch_bounds__(256) void crf_parallel_kernel(
    const float* __restrict__ em, const int* __restrict__ amask,
    const int* __restrict__ spos, const int* __restrict__ epos,
    const float* __restrict__ startT, const float* __restrict__ endT,
    const float* __restrict__ trans, float* __restrict__ out)
{
    __shared__ float4 mats[B_][64];
    __shared__ float numred[B_][64];
    __shared__ float cntred[B_][64];
    __shared__ float llh[B_];
    const int tid = threadIdx.x;
    const int s = tid >> 6;
    const int j = tid & 63;
    const float NEG = -1e30f;

    const int sp = spos[s], ep = epos[s];
    const bool valid = (sp >= 0) && (sp < S_) && (ep >= 0) && (ep < S_) && (sp <= ep);
    const float* e = em + (size_t)s * S_ * 2;
    const int* mk = amask + s * S_;
    const float t00 = trans[0], t01 = trans[1], t10 = trans[2], t11 = trans[3];

    float4 C = make_float4(0.f, NEG, NEG, 0.f);
    float num = 0.f, cnt = 0.f;
#pragma unroll
    for (int k = 0; k < 8; k++) {
        const int t = j * 8 + 1 + k;
        float4 Mt = make_float4(0.f, NEG, NEG, 0.f);
        if (t < S_ && mk[t]) {
            const float e0 = e[2 * t], e1 = e[2 * t + 1];
            Mt = make_float4(t00 + e0, t01 + e1, t10 + e0, t11 + e1);
            const int tp = (valid && (t - 1) >= sp && (t - 1) <= ep) ? 1 : 0;
            const int tc = (valid && t >= sp && t <= ep) ? 1 : 0;
            const float tr = tp ? (tc ? t11 : t10) : (tc ? t01 : t00);
            num += tr + (tc ? e1 : e0);
            cnt += 1.f;
        }
        C = (k == 0) ? Mt : lsem_comb(C, Mt);
    }
    if (j == 0) {
        const int tag0 = (valid && 0 >= sp && 0 <= ep) ? 1 : 0;
        num += startT[tag0] + e[tag0];
        cnt += mk[0] ? 1.f : 0.f;
    }
    mats[s][j] = C;
    numred[s][j] = num;
    cntred[s][j] = cnt;
    __syncthreads();

    for (int st = 32; st >= 1; st >>= 1) {
        float4 a, b;
        const bool act = (j < st);
        if (act) { a = mats[s][2 * j]; b = mats[s][2 * j + 1]; }
        __syncthreads();
        if (act) mats[s][j] = lsem_comb(a, b);
        __syncthreads();
    }
    for (int st = 32; st >= 1; st >>= 1) {
        if (j < st) {
            numred[s][j] += numred[s][j + st];
            cntred[s][j] += cntred[s][j + st];
        }
        __syncthreads();
    }

    if (j == 0) {
        float numT = numred[s][0];
        const int last_idx = (int)(cntred[s][0] + 0.5f) - 1;
        const int ltag = (valid && last_idx >= sp && last_idx <= ep) ? 1 : 0;
        numT += endT[ltag];
        const float a00 = startT[0] + e[0];
        const float a01 = startT[1] + e[1];
        const float4 P = mats[s][0];
        const float aF0 = lse2(a00 + P.x, a01 + P.z);
        const float aF1 = lse2(a00 + P.y, a01 + P.w);
        const float logZ = lse2(aF0 + endT[0], aF1 + endT[1]);
        llh[s] = numT - logZ;
    }
    __syncthreads();
    if (tid == 0)
        out[0] = -(llh[0] + llh[1] + llh[2] + llh[3]);
}

// ---------------------------------------------------------------------------
// Launch
// ---------------------------------------------------------------------------
extern "C" void kernel_launch(void* const* d_in, const int* in_sizes, int n_in,
                              void* d_out, int out_size, void* d_ws, size_t ws_size,
                              hipStream_t stream)
{
    const int*   input_ids  = (const int*)  d_in[0];
    const int*   attn_mask  = (const int*)  d_in[1];
    const int*   token_type = (const int*)  d_in[2];
    const int*   start_pos  = (const int*)  d_in[3];
    const int*   end_pos    = (const int*)  d_in[4];
    const float* word_emb   = (const float*)d_in[5];
    const float* pos_emb    = (const float*)d_in[6];
    const float* type_emb   = (const float*)d_in[7];
    const float* emb_ln_g   = (const float*)d_in[8];
    const float* emb_ln_b   = (const float*)d_in[9];
    const float* Wq         = (const float*)d_in[10];
    const float* bq         = (const float*)d_in[11];
    const float* Wk         = (const float*)d_in[12];
    const float* bk         = (const float*)d_in[13];
    const float* Wv         = (const float*)d_in[14];
    const float* bv         = (const float*)d_in[15];
    const float* Wo         = (const float*)d_in[16];
    const float* bo         = (const float*)d_in[17];
    const float* ln1_g      = (const float*)d_in[18];
    const float* ln1_b      = (const float*)d_in[19];
    const float* W1         = (const float*)d_in[20];
    const float* b1         = (const float*)d_in[21];
    const float* W2         = (const float*)d_in[22];
    const float* b2         = (const float*)d_in[23];
    const float* ln2_g      = (const float*)d_in[24];
    const float* ln2_b      = (const float*)d_in[25];
    const float* qa_w       = (const float*)d_in[26];
    const float* qa_b       = (const float*)d_in[27];
    const float* crf_start  = (const float*)d_in[28];
    const float* crf_end    = (const float*)d_in[29];
    const float* crf_trans  = (const float*)d_in[30];
    float* out = (float*)d_out;

    // Workspace carve-up
    float*  x      = (float*)d_ws;                                  // M*H
    float*  tmp768 = x + (size_t)M_ * H_;                           // 4 * M*H (split-K slabs)
    float*  emis   = tmp768 + (size_t)4 * M_ * H_;                  // M*2
    float*  b_qkv  = emis + (size_t)M_ * 2;                         // L*2304
    ushort* xb     = (ushort*)(b_qkv + (size_t)L_ * QKVN);          // M*H
    ushort* qkvb   = xb + (size_t)M_ * H_;                          // M*2304
    ushort* ctxb   = qkvb + (size_t)M_ * QKVN;                      // M*H
    ushort* hb     = ctxb + (size_t)M_ * H_;                        // M*FF
    ushort* Wt_qkv = hb + (size_t)M_ * FF_;                         // L*2304*768 (tiled)
    ushort* Wt_o   = Wt_qkv + (size_t)L_ * QKVN * H_;               // L*768*768  (tiled)
    ushort* Wt_1   = Wt_o + (size_t)L_ * H_ * H_;                   // L*768*3072 (tiled)
    ushort* Wt_2   = Wt_1 + (size_t)L_ * H_ * FF_;                  // L*3072*768 (tiled)

    dim3 blk(256);

    // all-layer weight prep + embedding in one launch
    prep_embed_kernel<<<dim3(2048, L_ + 1), blk, 0, stream>>>(
        Wq, Wk, Wv, Wo, W1, W2, bq, bk, bv,
        Wt_qkv, Wt_o, Wt_1, Wt_2, b_qkv,
        input_ids, token_type, word_emb, pos_emb, type_emb,
        emb_ln_g, emb_ln_b, x, (__hip_bfloat16*)xb);

    const dim3 gQKV(QKVN / TN, M_ / TM);      // 18 x 16
    const dim3 gO(H_ / TN, M_ / TM, 2);       //  6 x 16 x 2 (split-K)
    const dim3 gF1(FF_ / TN, M_ / TM);        // 24 x 16
    const dim3 gF2(H_ / TN, M_ / TM, 4);      //  6 x 16 x 4 (split-K)
    const dim3 gA(S_ / 64, NH_, B_);          //  8 x 12 x 4

    for (int l = 0; l < L_; l++) {
        gemm_mfma_kernel<0, 1, 1><<<gQKV, blk, 0, stream>>>(
            xb, Wt_qkv + (size_t)l * QKVN * H_, b_qkv + (size_t)l * QKVN,
            qkvb, M_, H_, QKVN);

        flash_attn_mfma_kernel<<<gA, blk, 0, stream>>>(
            qkvb, attn_mask, (__hip_bfloat16*)ctxb);

        gemm_mfma_kernel<0, 0, 2><<<gO, blk, 0, stream>>>(
            ctxb, Wt_o + (size_t)l * H_ * H_, bo + l * H_, tmp768, M_, H_, H_);
        add_ln_kernel<2, 0><<<M_, blk, 0, stream>>>(
            x, tmp768, ln1_g + l * H_, ln1_b + l * H_,
            (__hip_bfloat16*)xb, nullptr, nullptr, nullptr);

        gemm_mfma_kernel<1, 1, 1><<<gF1, blk, 0, stream>>>(
            xb, Wt_1 + (size_t)l * H_ * FF_, b1 + l * FF_, hb, M_, H_, FF_);
        gemm_mfma_kernel<0, 0, 4><<<gF2, blk, 0, stream>>>(
            hb, Wt_2 + (size_t)l * FF_ * H_, b2 + l * H_, tmp768, M_, FF_, H_);
        if (l == L_ - 1)
            add_ln_kernel<4, 1><<<M_, blk, 0, stream>>>(
                x, tmp768, ln2_g + l * H_, ln2_b + l * H_,
                (__hip_bfloat16*)xb, qa_w, qa_b, emis);
        else
            add_ln_kernel<4, 0><<<M_, blk, 0, stream>>>(
                x, tmp768, ln2_g + l * H_, ln2_b + l * H_,
                (__hip_bfloat16*)xb, nullptr, nullptr, nullptr);
    }

    crf_parallel_kernel<<<1, 256, 0, stream>>>(emis, attn_mask, start_pos, end_pos,
                                               crf_start, crf_end, crf_trans, out);
}